// Round 1
// baseline (3619.630 us; speedup 1.0000x reference)
//
#include <hip/hip_runtime.h>
#include <math.h>

// CollapseEngine fused kernel (f32, correctness-first baseline).
// All 6 layers fused in one launch; row-block resident in LDS.
// Roofline: 206 GFLOP f32 -> ~1.31 ms floor on vector ALU (no fp32 MFMA on CDNA4).

#define DIMX 256
#define NL 6
#define RPB 64      // rows per block
#define NTHR 512    // 8 waves; wave w owns rows 8w..8w+7
#define DD 16       // k-chunk staged in LDS per GEMM step

__device__ __forceinline__ float dot4(float4 a, float4 b) {
    return fmaf(a.x, b.x, fmaf(a.y, b.y, fmaf(a.z, b.z, a.w * b.w)));
}

// GEMM chunk loop: acc[rl][i] += sum_d SRC[row][d] * Wp[col][d]
// wbuf staged transposed ([d][c]) so wave reads are contiguous (conflict-free);
// SRC reads are wave-uniform (broadcast). W chunk prefetched one step ahead.
#define GEMM_CHUNKS(SRC, WPTR)                                              \
    {                                                                        \
        const float* Wp = (WPTR);                                            \
        float4 u0 = *(const float4*)&Wp[cW*DIMX + dh];                       \
        float4 u1 = *(const float4*)&Wp[cW*DIMX + dh + 4];                   \
        for (int kc = 0; kc < DIMX; kc += DD) {                              \
            __syncthreads();  /* wbuf consumers of prev chunk done */        \
            wbuf[dh+0][cW]=u0.x; wbuf[dh+1][cW]=u0.y;                        \
            wbuf[dh+2][cW]=u0.z; wbuf[dh+3][cW]=u0.w;                        \
            wbuf[dh+4][cW]=u1.x; wbuf[dh+5][cW]=u1.y;                        \
            wbuf[dh+6][cW]=u1.z; wbuf[dh+7][cW]=u1.w;                        \
            if (kc + DD < DIMX) {                                            \
                u0 = *(const float4*)&Wp[cW*DIMX + kc + DD + dh];            \
                u1 = *(const float4*)&Wp[cW*DIMX + kc + DD + dh + 4];        \
            }                                                                \
            __syncthreads();  /* wbuf ready */                               \
            _Pragma("unroll")                                                \
            for (int d4 = 0; d4 < DD; d4 += 4) {                             \
                float4 w0 = *(const float4*)&wbuf[d4+0][c0];                 \
                float4 w1 = *(const float4*)&wbuf[d4+1][c0];                 \
                float4 w2 = *(const float4*)&wbuf[d4+2][c0];                 \
                float4 w3 = *(const float4*)&wbuf[d4+3][c0];                 \
                _Pragma("unroll")                                            \
                for (int rl = 0; rl < 8; ++rl) {                             \
                    float4 hv = *(const float4*)&SRC[rbase+rl][kc+d4];       \
                    acc[rl][0]=fmaf(hv.x,w0.x,acc[rl][0]);                   \
                    acc[rl][1]=fmaf(hv.x,w0.y,acc[rl][1]);                   \
                    acc[rl][2]=fmaf(hv.x,w0.z,acc[rl][2]);                   \
                    acc[rl][3]=fmaf(hv.x,w0.w,acc[rl][3]);                   \
                    acc[rl][0]=fmaf(hv.y,w1.x,acc[rl][0]);                   \
                    acc[rl][1]=fmaf(hv.y,w1.y,acc[rl][1]);                   \
                    acc[rl][2]=fmaf(hv.y,w1.z,acc[rl][2]);                   \
                    acc[rl][3]=fmaf(hv.y,w1.w,acc[rl][3]);                   \
                    acc[rl][0]=fmaf(hv.z,w2.x,acc[rl][0]);                   \
                    acc[rl][1]=fmaf(hv.z,w2.y,acc[rl][1]);                   \
                    acc[rl][2]=fmaf(hv.z,w2.z,acc[rl][2]);                   \
                    acc[rl][3]=fmaf(hv.z,w2.w,acc[rl][3]);                   \
                    acc[rl][0]=fmaf(hv.w,w3.x,acc[rl][0]);                   \
                    acc[rl][1]=fmaf(hv.w,w3.y,acc[rl][1]);                   \
                    acc[rl][2]=fmaf(hv.w,w3.z,acc[rl][2]);                   \
                    acc[rl][3]=fmaf(hv.w,w3.w,acc[rl][3]);                   \
                }                                                            \
            }                                                                \
        }                                                                    \
    }

__global__ __launch_bounds__(NTHR, 2)
void collapse_fused(const float* __restrict__ h0,
                    const float* __restrict__ W1,
                    const float* __restrict__ b1,
                    const float* __restrict__ W2,
                    const float* __restrict__ b2,
                    const float* __restrict__ anchors,
                    float* __restrict__ out_h,
                    float* __restrict__ out_align,
                    float* __restrict__ out_div,
                    float* __restrict__ out_tens,
                    int B)
{
    __shared__ float hs[RPB][DIMX];     // 64 KiB: row state (wave-private rows)
    __shared__ float ts[RPB][DIMX];     // 64 KiB: tanh(h@W1^T+b1)
    __shared__ float wbuf[DD][DIMX];    // 16 KiB: transposed W chunk [d][c]
    __shared__ float an[3][DIMX];       //  3 KiB: normalized anchors

    const int tid   = threadIdx.x;
    const int wave  = tid >> 6;
    const int lane  = tid & 63;
    const int c0    = lane << 2;        // this thread's 4 output columns
    const int rbase = wave << 3;        // this wave's 8 rows
    const long long b0 = (long long)blockIdx.x * RPB;

    // normalize anchors once (waves 0..2, one anchor each)
    if (wave < 3) {
        float4 av = *(const float4*)&anchors[wave * DIMX + c0];
        float ss = dot4(av, av);
        #pragma unroll
        for (int m = 1; m < 64; m <<= 1) ss += __shfl_xor(ss, m, 64);
        float inv = 1.0f / fmaxf(sqrtf(ss), 1e-12f);
        av.x *= inv; av.y *= inv; av.z *= inv; av.w *= inv;
        *(float4*)&an[wave][c0] = av;
    }

    // load h tile (coalesced float4, wave loads its own 8 rows)
    #pragma unroll
    for (int rl = 0; rl < 8; ++rl) {
        int r = rbase + rl;
        *(float4*)&hs[r][c0] = *(const float4*)&h0[(b0 + r) * DIMX + c0];
    }

    const float4 b1v = *(const float4*)&b1[c0];
    const float4 b2v = *(const float4*)&b2[c0];

    // cooperative W-stage mapping: thread loads 8 contiguous floats of row cW
    const int cW = tid >> 1;            // 0..255 (W row = output col)
    const int dh = (tid & 1) << 3;      // 0 or 8 within the 16-wide k-chunk

    __syncthreads();

    for (int layer = 0; layer < NL; ++layer) {
        // ---------- per-row stats, traces, force coefficients ----------
        float coef[8][3];
        float4 A0 = *(const float4*)&an[0][c0];
        float4 A1 = *(const float4*)&an[1][c0];
        float4 A2 = *(const float4*)&an[2][c0];
        #pragma unroll
        for (int rl = 0; rl < 8; ++rl) {
            int r = rbase + rl;
            float4 hv = *(const float4*)&hs[r][c0];
            float p[7];
            p[0] = dot4(hv, hv);
            p[1] = dot4(hv, A0);
            p[2] = dot4(hv, A1);
            p[3] = dot4(hv, A2);
            float4 e;
            e.x = hv.x-A0.x; e.y = hv.y-A0.y; e.z = hv.z-A0.z; e.w = hv.w-A0.w;
            p[4] = dot4(e, e);
            e.x = hv.x-A1.x; e.y = hv.y-A1.y; e.z = hv.z-A1.z; e.w = hv.w-A1.w;
            p[5] = dot4(e, e);
            e.x = hv.x-A2.x; e.y = hv.y-A2.y; e.z = hv.z-A2.z; e.w = hv.w-A2.w;
            p[6] = dot4(e, e);
            #pragma unroll
            for (int m = 1; m < 64; m <<= 1) {
                #pragma unroll
                for (int j = 0; j < 7; ++j) p[j] += __shfl_xor(p[j], m, 64);
            }
            float inv_rn = 1.0f / fmaxf(sqrtf(p[0]), 1e-12f);
            float al0 = p[1]*inv_rn, al1 = p[2]*inv_rn, al2 = p[3]*inv_rn;
            float dv0 = 1.0f-al0, dv1 = 1.0f-al1, dv2 = 1.0f-al2;
            coef[rl][0] = -0.10f * dv0 / fmaxf(sqrtf(p[4]), 1e-12f);
            coef[rl][1] = -0.10f * dv1 / fmaxf(sqrtf(p[5]), 1e-12f);
            coef[rl][2] = -0.05f * dv2 / fmaxf(sqrtf(p[6]), 1e-12f);
            if (lane == 0) {
                long long tb = ((long long)layer * B + (b0 + r)) * 3;
                out_align[tb+0] = al0; out_align[tb+1] = al1; out_align[tb+2] = al2;
                out_div[tb+0]   = dv0; out_div[tb+1]   = dv1; out_div[tb+2]   = dv2;
                out_tens[tb+0]  = dv0*dv0; out_tens[tb+1] = dv1*dv1; out_tens[tb+2] = dv2*dv2;
            }
        }

        float acc[8][4];
        #pragma unroll
        for (int rl = 0; rl < 8; ++rl) {
            #pragma unroll
            for (int i = 0; i < 4; ++i) acc[rl][i] = 0.0f;
        }

        // ---------- GEMM1: acc = hs @ W1^T ----------
        GEMM_CHUNKS(hs, W1)

        // tanh + bias -> ts (wave-private rows, no barrier needed)
        #pragma unroll
        for (int rl = 0; rl < 8; ++rl) {
            float4 tv;
            tv.x = tanhf(acc[rl][0] + b1v.x);
            tv.y = tanhf(acc[rl][1] + b1v.y);
            tv.z = tanhf(acc[rl][2] + b1v.z);
            tv.w = tanhf(acc[rl][3] + b1v.w);
            *(float4*)&ts[rbase+rl][c0] = tv;
        }

        // ---------- init acc2 = h + b2 + force ----------
        #pragma unroll
        for (int rl = 0; rl < 8; ++rl) {
            int r = rbase + rl;
            float4 hv = *(const float4*)&hs[r][c0];
            acc[rl][0] = hv.x + b2v.x + coef[rl][0]*(hv.x-A0.x) + coef[rl][1]*(hv.x-A1.x) + coef[rl][2]*(hv.x-A2.x);
            acc[rl][1] = hv.y + b2v.y + coef[rl][0]*(hv.y-A0.y) + coef[rl][1]*(hv.y-A1.y) + coef[rl][2]*(hv.y-A2.y);
            acc[rl][2] = hv.z + b2v.z + coef[rl][0]*(hv.z-A0.z) + coef[rl][1]*(hv.z-A1.z) + coef[rl][2]*(hv.z-A2.z);
            acc[rl][3] = hv.w + b2v.w + coef[rl][0]*(hv.w-A0.w) + coef[rl][1]*(hv.w-A1.w) + coef[rl][2]*(hv.w-A2.w);
        }

        // ---------- GEMM2: acc += ts @ W2^T  -> h_new ----------
        GEMM_CHUNKS(ts, W2)

        // ---------- norm clip + store ----------
        #pragma unroll
        for (int rl = 0; rl < 8; ++rl) {
            float ss = acc[rl][0]*acc[rl][0] + acc[rl][1]*acc[rl][1]
                     + acc[rl][2]*acc[rl][2] + acc[rl][3]*acc[rl][3];
            #pragma unroll
            for (int m = 1; m < 64; m <<= 1) ss += __shfl_xor(ss, m, 64);
            float n = sqrtf(ss);
            float sc = (n > 10.0f) ? (10.0f / (n + 1e-8f)) : 1.0f;
            float4 hv;
            hv.x = acc[rl][0]*sc; hv.y = acc[rl][1]*sc;
            hv.z = acc[rl][2]*sc; hv.w = acc[rl][3]*sc;
            if (layer == NL-1) {
                *(float4*)&out_h[(b0 + rbase + rl)*DIMX + c0] = hv;
            } else {
                *(float4*)&hs[rbase+rl][c0] = hv;
            }
        }
        // no barrier needed here: hs/ts are wave-private; wbuf is protected by
        // the barrier at the top of the next GEMM chunk loop.
    }
}

extern "C" void kernel_launch(void* const* d_in, const int* in_sizes, int n_in,
                              void* d_out, int out_size, void* d_ws, size_t ws_size,
                              hipStream_t stream) {
    const float* h0      = (const float*)d_in[0];
    const float* W1      = (const float*)d_in[1];
    const float* b1      = (const float*)d_in[2];
    const float* W2      = (const float*)d_in[3];
    const float* b2      = (const float*)d_in[4];
    const float* anchors = (const float*)d_in[5];
    const int B = in_sizes[0] / DIMX;

    float* out_h     = (float*)d_out;
    float* out_align = out_h + (long long)B * DIMX;
    float* out_div   = out_align + (long long)NL * B * 3;
    float* out_tens  = out_div   + (long long)NL * B * 3;

    dim3 grid(B / RPB), block(NTHR);
    hipLaunchKernelGGL(collapse_fused, grid, block, 0, stream,
                       h0, W1, b1, W2, b2, anchors,
                       out_h, out_align, out_div, out_tens, B);
}